// Round 13
// baseline (276.264 us; speedup 1.0000x reference)
//
#include <hip/hip_runtime.h>
#include <hip/hip_bf16.h>
#include <stdint.h>

// QuantizedCpuLinear: y = scale * (x @ wq^T)
// x: f32 [8192,4096]; wq int8-valued delivered as int32 [4096,4096] (K contig);
// out f32 [8192,4096]. bf16 MFMA GEMM, 256x256 tile, BK=64, 8 waves.
// R13 = R12 (best: 232.5us GEMM, 52.6% MfmaUtil; 3-buf B, ONE barrier +
// counted vmcnt(4)/tile) + (a) non-temporal C stores (C is write-once: keep
// it out of L3 so A/B panels stay resident -> cut the ~200MB HBM re-fetch),
// (b) non-temporal X/Wq loads in convert (read-once), (c) all 8 DMA issues
// at tile top (stageB(preB,t+2) is hazard-free there; ledger unchanged).
// Swizzled LDS (T2), counted vmcnt (T4), setprio (T5), XCD swz (T1).

#define M_DIM 8192
#define N_DIM 4096
#define K_DIM 4096
#define BM 256
#define BN 256
#define BK 64
#define NT (K_DIM / BK)          // 64

typedef __attribute__((ext_vector_type(4))) float    f32x4;
typedef __attribute__((ext_vector_type(4))) int      i32x4;
typedef __attribute__((ext_vector_type(2))) uint32_t u32x2;
typedef __attribute__((ext_vector_type(4))) uint32_t u32x4;
typedef __attribute__((ext_vector_type(8))) short    bf16x8;
typedef uint32_t u32;

__device__ __forceinline__ u32 fbits(float f) { return __builtin_bit_cast(u32, f); }
// two f32 -> two bf16 by truncation (1 v_perm_b32); exact for int8-valued floats.
__device__ __forceinline__ u32 pack_bf16_trunc(float lo, float hi) {
    return __builtin_amdgcn_perm(fbits(hi), fbits(lo), 0x07060302u);
}
// LDS byte address for logical (row, byte-col) in a [256][128B] tile (fallback).
__device__ __forceinline__ int swzb(int row, int bytecol) {
    return row * 128 + (bytecol ^ ((row & 7) << 4));
}

// global_load_lds, 16B per lane. LDS dst is wave-uniform; HW writes dst+lane*16.
__device__ __forceinline__ void gload_lds16(const void* g, void* s) {
    __builtin_amdgcn_global_load_lds(
        (const __attribute__((address_space(1))) void*)(uintptr_t)g,
        (__attribute__((address_space(3))) void*)(u32)(uintptr_t)s, 16, 0, 0);
}

#define WAIT_VM4()   do { asm volatile("s_waitcnt vmcnt(4)" ::: "memory");   \
                          __builtin_amdgcn_sched_barrier(0); } while (0)
#define WAIT_VM0()   do { asm volatile("s_waitcnt vmcnt(0)" ::: "memory");   \
                          __builtin_amdgcn_sched_barrier(0); } while (0)
#define BARRIER()    do { __builtin_amdgcn_s_barrier();                      \
                          __builtin_amdgcn_sched_barrier(0); } while (0)

// ---- merged pre-convert: X f32 -> bf16 and W int32 -> bf16, one launch ----
// Blocks [0, NXB): X path (8 f32/thread). Blocks [NXB, NXB+NWB): W path
// (8 int32/thread). Branch is block-uniform -> no divergence. Inputs are
// read-once -> non-temporal loads (don't pollute L3); outputs are re-read by
// the GEMM -> normal (cacheable) stores.
#define NXB ((M_DIM * K_DIM) / (8 * 256))   // 16384
#define NWB ((N_DIM * K_DIM) / (8 * 256))   // 8192
__global__ __launch_bounds__(256)
void qlin_convert_xw(const float* __restrict__ X, const int* __restrict__ Wq,
                     short* __restrict__ Xb, short* __restrict__ Wb)
{
    const int b = (int)blockIdx.x;
    if (b < NXB) {
        const size_t i = (size_t)b * 256 + threadIdx.x;
        f32x4 a = __builtin_nontemporal_load((const f32x4*)X + 2 * i);
        f32x4 c = __builtin_nontemporal_load((const f32x4*)X + 2 * i + 1);
        u32x4 q;
        q[0] = pack_bf16_trunc(a[0], a[1]);
        q[1] = pack_bf16_trunc(a[2], a[3]);
        q[2] = pack_bf16_trunc(c[0], c[1]);
        q[3] = pack_bf16_trunc(c[2], c[3]);
        ((u32x4*)Xb)[i] = q;
    } else {
        const size_t i = (size_t)(b - NXB) * 256 + threadIdx.x;
        i32x4 w0 = __builtin_nontemporal_load((const i32x4*)Wq + 2 * i);
        i32x4 w1 = __builtin_nontemporal_load((const i32x4*)Wq + 2 * i + 1);
        u32x4 q;
        q[0] = pack_bf16_trunc((float)w0[0], (float)w0[1]);
        q[1] = pack_bf16_trunc((float)w0[2], (float)w0[3]);
        q[2] = pack_bf16_trunc((float)w1[0], (float)w1[1]);
        q[3] = pack_bf16_trunc((float)w1[2], (float)w1[3]);
        ((u32x4*)Wb)[i] = q;
    }
}

// ===================== main pipelined GEMM (bf16 inputs) =====================
// LDS: A [2 dbuf][2 half][128 rows][128 B] = 64 KiB; B [3 bufs][2 half][...]
// = 96 KiB; 160 KiB total (full pool, 1 block/CU as before).
// Logical (row,bytecol) at physical row*128 + (bytecol ^ ((row&7)<<4)); global
// source pre-swizzled with the same XOR so the linear DMA write lands swizzled
// (rule 21).
__global__ __launch_bounds__(512, 2)
void qlin_gemm_p(const short* __restrict__ A, const short* __restrict__ B,
                 const float* __restrict__ scale_p, float* __restrict__ C)
{
    __shared__ __align__(16) char As[2][2][128 * 128];   // 64 KiB
    __shared__ __align__(16) char Bs[3][2][128 * 128];   // 96 KiB

    const int tid = threadIdx.x;
    // XCD swizzle: nwg = 512, divisible by 8 -> bijective
    const int nwg = (M_DIM / BM) * (N_DIM / BN);   // 512
    const int cpx = nwg / 8;
    const int bid = ((int)blockIdx.x % 8) * cpx + (int)blockIdx.x / 8;
    const int tileM = (bid / (N_DIM / BN)) * BM;
    const int tileN = (bid % (N_DIM / BN)) * BN;

    const int lane = tid & 63;
    const int wid  = tid >> 6;       // 0..7
    const int wr   = wid >> 2;       // 0..1  (wave covers 128 M-rows = A half wr)
    const int wc   = wid & 3;        // 0..3  (wave covers 64 N-cols)
    const int lr   = lane & 15;
    const int lq   = lane >> 4;

    // staging source addressing (per lane): 8 rows x 128B per wave-issue
    const int srow = lane >> 3;                    // 0..7
    const int scol = ((lane & 7) ^ srow) << 4;     // inverse-swizzled byte col
    const char* Ag = (const char*)A;
    const char* Bg = (const char*)B;

    // stage one half-tile (2 x global_load_lds per thread)
    auto stageA = [&](int buf, int h, int kt) {
#pragma unroll
        for (int j = 0; j < 2; ++j) {
            const int seg = wid * 2 + j;           // 0..15
            const char* src = Ag + (size_t)(tileM + h * 128 + seg * 8 + srow) * (K_DIM * 2)
                                 + kt * (BK * 2) + scol;
            gload_lds16(src, &As[buf][h][seg * 1024]);
        }
    };
    auto stageB = [&](int buf, int h, int kt) {
#pragma unroll
        for (int j = 0; j < 2; ++j) {
            const int seg = wid * 2 + j;
            const char* src = Bg + (size_t)(tileN + h * 128 + seg * 8 + srow) * (K_DIM * 2)
                                 + kt * (BK * 2) + scol;
            gload_lds16(src, &Bs[buf][h][seg * 1024]);
        }
    };

    // ---- fragments ----
    f32x4  acc[8][4] = {};
    bf16x8 afr[4][2];                // reused for mb0-3 then mb4-7 (reg economy)
    bf16x8 b0fr[2][2], b2fr[2][2];

    auto swzh = [](int row, int bc) { return row * 128 + (bc ^ ((row & 7) << 4)); };
    auto ldA = [&](int buf, int mb) {
#pragma unroll
        for (int m = 0; m < 4; ++m) {
            const int row = (mb + m) * 16 + lr;                 // 0..127 in half wr
#pragma unroll
            for (int ks = 0; ks < 2; ++ks)
                afr[m][ks] = *(const bf16x8*)&As[buf][wr][swzh(row, ks * 64 + lq * 16)];
        }
    };
    auto ldB = [&](int buf, int nb, bf16x8 (&bf)[2][2]) {
#pragma unroll
        for (int n = 0; n < 2; ++n) {
            const int r = wc * 64 + (nb + n) * 16 + lr;         // 0..255
#pragma unroll
            for (int ks = 0; ks < 2; ++ks)
                bf[n][ks] = *(const bf16x8*)&Bs[buf][r >> 7][swzh(r & 127, ks * 64 + lq * 16)];
        }
    };
    // ks OUTERMOST: dependent MFMAs spaced 8 apart; per-element accumulation
    // order unchanged (ks0 then ks1) -> bit-identical.
    auto quad = [&](int mb, int nb, bf16x8 (&bf)[2][2]) {
        __builtin_amdgcn_s_setprio(1);
#pragma unroll
        for (int ks = 0; ks < 2; ++ks)
#pragma unroll
            for (int m = 0; m < 4; ++m)
#pragma unroll
                for (int n = 0; n < 2; ++n)
                    acc[mb + m][nb + n] = __builtin_amdgcn_mfma_f32_16x16x32_bf16(
                        afr[m][ks], bf[n][ks], acc[mb + m][nb + n], 0, 0, 0);
        __builtin_amdgcn_s_setprio(0);
    };

    // ---- prologue: tile0 A->A0, B->B3[0]; tile1 B->B3[1]; 4 left in flight --
    stageA(0, 0, 0); stageA(0, 1, 0);
    stageB(0, 0, 0); stageB(0, 1, 0);
    stageB(1, 0, 1); stageB(1, 1, 1);
    WAIT_VM4();          // tile0's 8 loads landed; tile1's 4 B loads in flight
    BARRIER();

    // ---- main loop: ONE barrier + one counted vmcnt per K-tile ----
    // Entry invariant at tile t: A(t) in A-buf t&1, B(t) in B3[t%3], all landed
    // (end-of-t-1 vmcnt(4) drained everything except B(t+1)); B(t+1)[4] in
    // flight toward B3[(t+1)%3].
    // ALL staging at tile top (both hazard-free):
    //   stageA(nxtA,t+1): A-buf nxtA last read in tile t-1, behind the barrier.
    //   stageB(preB,t+2): B3[preB] last read in tile t-1, behind the barrier;
    //     NO reader of B3[preB] in tile t.
    // end-of-t vmcnt(4): per-wave FIFO = B(t+1)[4, issued t-1 top] + A(t+1)[4]
    // + B(t+2)[4] = 12; wait(4) drains B(t+1) (2-tile lead) and A(t+1)
    // (1-tile lead), leaves B(t+2) in flight.
    int curB = 0, preB = 2;          // curB = kt%3, preB = (kt+2)%3
#pragma unroll 1
    for (int kt = 0; kt < NT; ++kt) {
        const int curA = kt & 1, nxtA = curA ^ 1;

        if (kt + 1 < NT) { stageA(nxtA, 0, kt + 1); stageA(nxtA, 1, kt + 1); }
        if (kt + 2 < NT) { stageB(preB, 0, kt + 2); stageB(preB, 1, kt + 2); }

        // reads of tile t, staggered between MFMA clusters
        ldA(curA, 0);
        ldB(curB, 0, b0fr);
        ldB(curB, 2, b2fr);

        quad(0, 0, b0fr);            // MFMA starts as soon as first frags land
        quad(0, 2, b2fr);

        ldA(curA, 4);                // reuse afr for mb4-7

        quad(4, 2, b2fr);
        quad(4, 0, b0fr);

        if (kt + 2 < NT)      { WAIT_VM4(); }   // t+1 landed; B(t+2) in flight
        else if (kt + 1 < NT) { WAIT_VM0(); }   // tail: drain last tile
        BARRIER();                   // single tile-boundary sync

        curB = (curB == 2) ? 0 : curB + 1;
        preB = (preB == 2) ? 0 : preB + 1;
    }

    // ---- epilogue: C/D layout col=lane&15, row=(lane>>4)*4+reg ----
    // C is write-once, never re-read: non-temporal stores keep it out of L3
    // so A/B panels stay resident (cuts HBM re-fetch).
    const float scl = scale_p[0];
#pragma unroll
    for (int m = 0; m < 8; ++m) {
        const int gm0 = tileM + wr * 128 + m * 16 + lq * 4;
#pragma unroll
        for (int n = 0; n < 4; ++n) {
            const int gn = tileN + wc * 64 + n * 16 + lr;
            float* cp = C + (size_t)gm0 * N_DIM + gn;
#pragma unroll
            for (int r = 0; r < 4; ++r)
                __builtin_nontemporal_store(acc[m][n][r] * scl, cp + (size_t)r * N_DIM);
        }
    }
}

// ===================== fallback (no workspace): reg-staged kernel ============
#define TILE_BYTES (BM * BK * 2)
__global__ __launch_bounds__(512, 2)
void qlin_gemm8(const void* __restrict__ Asrc, const void* __restrict__ Bsrc,
                const float* __restrict__ scale_p, float* __restrict__ C)
{
    __shared__ char As[2 * TILE_BYTES];
    __shared__ char Bs[2 * TILE_BYTES];

    const int tid = threadIdx.x;
    const int nwg = (M_DIM / BM) * (N_DIM / BN);
    const int cpx = nwg / 8;
    const int bid = ((int)blockIdx.x % 8) * cpx + (int)blockIdx.x / 8;
    const int tileM = (bid / (N_DIM / BN)) * BM;
    const int tileN = (bid % (N_DIM / BN)) * BN;

    const int lane = tid & 63;
    const int wid  = tid >> 6;
    const int wr   = wid >> 2;
    const int wc   = wid & 3;
    const int lr   = lane & 15;
    const int lq   = lane >> 4;

    f32x4  aF[8]; i32x4 wF[8];

    const float* ag0 = (const float*)Asrc + (size_t)(tileM + (tid >> 4)) * K_DIM + (tid & 15) * 4;
    const int*   bg0 = (const int*)Bsrc  + (size_t)(tileN + (tid >> 4)) * K_DIM + (tid & 15) * 4;

    auto stage_load = [&](int kt) {
#pragma unroll
        for (int i = 0; i < 8; ++i)
            aF[i] = *(const f32x4*)(ag0 + (size_t)(32 * i) * K_DIM + kt * BK);
#pragma unroll
        for (int i = 0; i < 8; ++i)
            wF[i] = *(const i32x4*)(bg0 + (size_t)(32 * i) * K_DIM + kt * BK);
    };
    auto stage_writeA = [&](int nxt) {
        char* dst = As + nxt * TILE_BYTES;
#pragma unroll
        for (int i = 0; i < 8; ++i) {
            u32x2 p;
            p[0] = pack_bf16_trunc(aF[i][0], aF[i][1]);
            p[1] = pack_bf16_trunc(aF[i][2], aF[i][3]);
            *(u32x2*)(dst + swzb((tid >> 4) + 32 * i, (tid & 15) * 8)) = p;
        }
    };
    auto stage_writeB = [&](int nxt) {
        char* dst = Bs + nxt * TILE_BYTES;
#pragma unroll
        for (int i = 0; i < 8; ++i) {
            u32x2 p;
            p[0] = pack_bf16_trunc((float)wF[i][0], (float)wF[i][1]);
            p[1] = pack_bf16_trunc((float)wF[i][2], (float)wF[i][3]);
            *(u32x2*)(dst + swzb((tid >> 4) + 32 * i, (tid & 15) * 8)) = p;
        }
    };

    f32x4  acc[8][4] = {};
    bf16x8 afr[4][2], bfr[2][2];

    auto ldA = [&](const char* buf, int mb) {
#pragma unroll
        for (int m = 0; m < 4; ++m) {
            const int row = wr * 128 + (mb + m) * 16 + lr;
#pragma unroll
            for (int ks = 0; ks < 2; ++ks)
                afr[m][ks] = *(const bf16x8*)(buf + swzb(row, ks * 64 + lq * 16));
        }
    };
    auto ldB = [&](const char* buf, int nb) {
#pragma unroll
        for (int n = 0; n < 2; ++n) {
            const int row = wc * 64 + (nb + n) * 16 + lr;
#pragma unroll
            for (int ks = 0; ks < 2; ++ks)
                bfr[n][ks] = *(const bf16x8*)(buf + swzb(row, ks * 64 + lq * 16));
        }
    };
    auto quad = [&](int mb, int nb) {
        __builtin_amdgcn_s_setprio(1);
#pragma unroll
        for (int ks = 0; ks < 2; ++ks)
#pragma unroll
            for (int m = 0; m < 4; ++m)
#pragma unroll
                for (int n = 0; n < 2; ++n)
                    acc[mb + m][nb + n] = __builtin_amdgcn_mfma_f32_16x16x32_bf16(
                        afr[m][ks], bfr[n][ks], acc[mb + m][nb + n], 0, 0, 0);
        __builtin_amdgcn_s_setprio(0);
    };

    stage_load(0);
    stage_writeA(0);
    stage_writeB(0);
    __syncthreads();

#pragma unroll 1
    for (int kt = 0; kt < NT; ++kt) {
        const int cur = kt & 1, nxt = cur ^ 1;
        const bool more = (kt + 1) < NT;
        const char* Ab = As + cur * TILE_BYTES;
        const char* Bb = Bs + cur * TILE_BYTES;

        if (more) stage_load(kt + 1);

        ldA(Ab, 0); ldB(Bb, 0); quad(0, 0);
        ldB(Bb, 2);             quad(0, 2);
        ldA(Ab, 4);
        if (more) stage_writeA(nxt);
        quad(4, 2);
        ldB(Bb, 0);
        if (more) stage_writeB(nxt);
        quad(4, 0);

        __syncthreads();
    }

    const float scl = scale_p[0];
#pragma unroll
    for (int m = 0; m < 8; ++m) {
        const int gm0 = tileM + wr * 128 + m * 16 + lq * 4;
#pragma unroll
        for (int n = 0; n < 4; ++n) {
            const int gn = tileN + wc * 64 + n * 16 + lr;
            float* cp = C + (size_t)gm0 * N_DIM + gn;
#pragma unroll
            for (int r = 0; r < 4; ++r)
                cp[(size_t)r * N_DIM] = acc[m][n][r] * scl;
        }
    }
}

extern "C" void kernel_launch(void* const* d_in, const int* in_sizes, int n_in,
                              void* d_out, int out_size, void* d_ws, size_t ws_size,
                              hipStream_t stream)
{
    (void)in_sizes; (void)n_in; (void)out_size;
    const float* X     = (const float*)d_in[0];
    const int*   Wq    = (const int*)d_in[1];      // int8-valued, delivered as int32
    const float* scale = (const float*)d_in[2];
    float* C = (float*)d_out;

    const size_t xbytes = (size_t)M_DIM * K_DIM * sizeof(short);   // 64 MiB
    const size_t wbytes = (size_t)N_DIM * K_DIM * sizeof(short);   // 32 MiB

    if (ws_size >= xbytes + wbytes) {
        short* Xb = (short*)d_ws;
        short* Wb = (short*)((char*)d_ws + xbytes);
        qlin_convert_xw<<<dim3(NXB + NWB), dim3(256), 0, stream>>>(X, Wq, Xb, Wb);
        qlin_gemm_p<<<dim3((M_DIM / BM) * (N_DIM / BN)), dim3(512), 0, stream>>>(Xb, Wb, scale, C);
    } else {
        qlin_gemm8<<<dim3((M_DIM / BM) * (N_DIM / BN)), dim3(512), 0, stream>>>(X, Wq, scale, C);
    }
}

// Round 14
// 260.908 us; speedup vs baseline: 1.0589x; 1.0589x over previous
//
#include <hip/hip_runtime.h>
#include <hip/hip_bf16.h>
#include <stdint.h>

// QuantizedCpuLinear: y = scale * (x @ wq^T)
// x: f32 [8192,4096]; wq int8-valued delivered as int32 [4096,4096] (K contig);
// out f32 [8192,4096]. bf16 MFMA GEMM, 256x256 tile, BK=64, 8 waves.
// FINAL = R12 (session best: 261.8us total; GEMM 232.5us, 52.6% MfmaUtil).
// B in a THREE-buffer rotation (96 KiB) so B(t+2) stages into a buffer with
// no readers this tile -> ONE s_barrier + one counted vmcnt(4) per K-tile.
// A 2-dbuf (64 KiB); LDS = 160 KiB. Merged X/W pre-convert (one launch).
// R13's non-temporal stores REVERTED (measured: +37% WRITE_SIZE, -24us).
// Swizzled LDS (T2), counted vmcnt (T4), setprio (T5), XCD swz (T1).

#define M_DIM 8192
#define N_DIM 4096
#define K_DIM 4096
#define BM 256
#define BN 256
#define BK 64
#define NT (K_DIM / BK)          // 64

typedef __attribute__((ext_vector_type(4))) float    f32x4;
typedef __attribute__((ext_vector_type(4))) int      i32x4;
typedef __attribute__((ext_vector_type(2))) uint32_t u32x2;
typedef __attribute__((ext_vector_type(4))) uint32_t u32x4;
typedef __attribute__((ext_vector_type(8))) short    bf16x8;
typedef uint32_t u32;

__device__ __forceinline__ u32 fbits(float f) { return __builtin_bit_cast(u32, f); }
// two f32 -> two bf16 by truncation (1 v_perm_b32); exact for int8-valued floats.
__device__ __forceinline__ u32 pack_bf16_trunc(float lo, float hi) {
    return __builtin_amdgcn_perm(fbits(hi), fbits(lo), 0x07060302u);
}
// LDS byte address for logical (row, byte-col) in a [256][128B] tile (fallback).
__device__ __forceinline__ int swzb(int row, int bytecol) {
    return row * 128 + (bytecol ^ ((row & 7) << 4));
}

// global_load_lds, 16B per lane. LDS dst is wave-uniform; HW writes dst+lane*16.
__device__ __forceinline__ void gload_lds16(const void* g, void* s) {
    __builtin_amdgcn_global_load_lds(
        (const __attribute__((address_space(1))) void*)(uintptr_t)g,
        (__attribute__((address_space(3))) void*)(u32)(uintptr_t)s, 16, 0, 0);
}

#define WAIT_VM4()   do { asm volatile("s_waitcnt vmcnt(4)" ::: "memory");   \
                          __builtin_amdgcn_sched_barrier(0); } while (0)
#define WAIT_VM0()   do { asm volatile("s_waitcnt vmcnt(0)" ::: "memory");   \
                          __builtin_amdgcn_sched_barrier(0); } while (0)
#define BARRIER()    do { __builtin_amdgcn_s_barrier();                      \
                          __builtin_amdgcn_sched_barrier(0); } while (0)

// ---- merged pre-convert: X f32 -> bf16 and W int32 -> bf16, one launch ----
// Blocks [0, NXB): X path (8 f32/thread). Blocks [NXB, NXB+NWB): W path
// (8 int32/thread). Branch is block-uniform -> no divergence.
#define NXB ((M_DIM * K_DIM) / (8 * 256))   // 16384
#define NWB ((N_DIM * K_DIM) / (8 * 256))   // 8192
__global__ __launch_bounds__(256)
void qlin_convert_xw(const float* __restrict__ X, const int* __restrict__ Wq,
                     short* __restrict__ Xb, short* __restrict__ Wb)
{
    const int b = (int)blockIdx.x;
    if (b < NXB) {
        const size_t i = (size_t)b * 256 + threadIdx.x;
        f32x4 a = ((const f32x4*)X)[2 * i];
        f32x4 c = ((const f32x4*)X)[2 * i + 1];
        u32x4 q;
        q[0] = pack_bf16_trunc(a[0], a[1]);
        q[1] = pack_bf16_trunc(a[2], a[3]);
        q[2] = pack_bf16_trunc(c[0], c[1]);
        q[3] = pack_bf16_trunc(c[2], c[3]);
        ((u32x4*)Xb)[i] = q;
    } else {
        const size_t i = (size_t)(b - NXB) * 256 + threadIdx.x;
        i32x4 w0 = ((const i32x4*)Wq)[2 * i];
        i32x4 w1 = ((const i32x4*)Wq)[2 * i + 1];
        u32x4 q;
        q[0] = pack_bf16_trunc((float)w0[0], (float)w0[1]);
        q[1] = pack_bf16_trunc((float)w0[2], (float)w0[3]);
        q[2] = pack_bf16_trunc((float)w1[0], (float)w1[1]);
        q[3] = pack_bf16_trunc((float)w1[2], (float)w1[3]);
        ((u32x4*)Wb)[i] = q;
    }
}

// ===================== main pipelined GEMM (bf16 inputs) =====================
// LDS: A [2 dbuf][2 half][128 rows][128 B] = 64 KiB; B [3 bufs][2 half][...]
// = 96 KiB; 160 KiB total (full pool, 1 block/CU).
// Logical (row,bytecol) at physical row*128 + (bytecol ^ ((row&7)<<4)); global
// source pre-swizzled with the same XOR so the linear DMA write lands swizzled
// (rule 21).
__global__ __launch_bounds__(512, 2)
void qlin_gemm_p(const short* __restrict__ A, const short* __restrict__ B,
                 const float* __restrict__ scale_p, float* __restrict__ C)
{
    __shared__ __align__(16) char As[2][2][128 * 128];   // 64 KiB
    __shared__ __align__(16) char Bs[3][2][128 * 128];   // 96 KiB

    const int tid = threadIdx.x;
    // XCD swizzle: nwg = 512, divisible by 8 -> bijective
    const int nwg = (M_DIM / BM) * (N_DIM / BN);   // 512
    const int cpx = nwg / 8;
    const int bid = ((int)blockIdx.x % 8) * cpx + (int)blockIdx.x / 8;
    const int tileM = (bid / (N_DIM / BN)) * BM;
    const int tileN = (bid % (N_DIM / BN)) * BN;

    const int lane = tid & 63;
    const int wid  = tid >> 6;       // 0..7
    const int wr   = wid >> 2;       // 0..1  (wave covers 128 M-rows = A half wr)
    const int wc   = wid & 3;        // 0..3  (wave covers 64 N-cols)
    const int lr   = lane & 15;
    const int lq   = lane >> 4;

    // staging source addressing (per lane): 8 rows x 128B per wave-issue
    const int srow = lane >> 3;                    // 0..7
    const int scol = ((lane & 7) ^ srow) << 4;     // inverse-swizzled byte col
    const char* Ag = (const char*)A;
    const char* Bg = (const char*)B;

    // stage one half-tile (2 x global_load_lds per thread)
    auto stageA = [&](int buf, int h, int kt) {
#pragma unroll
        for (int j = 0; j < 2; ++j) {
            const int seg = wid * 2 + j;           // 0..15
            const char* src = Ag + (size_t)(tileM + h * 128 + seg * 8 + srow) * (K_DIM * 2)
                                 + kt * (BK * 2) + scol;
            gload_lds16(src, &As[buf][h][seg * 1024]);
        }
    };
    auto stageB = [&](int buf, int h, int kt) {
#pragma unroll
        for (int j = 0; j < 2; ++j) {
            const int seg = wid * 2 + j;
            const char* src = Bg + (size_t)(tileN + h * 128 + seg * 8 + srow) * (K_DIM * 2)
                                 + kt * (BK * 2) + scol;
            gload_lds16(src, &Bs[buf][h][seg * 1024]);
        }
    };

    // ---- fragments ----
    f32x4  acc[8][4] = {};
    bf16x8 afr[4][2];                // reused for mb0-3 then mb4-7 (reg economy)
    bf16x8 b0fr[2][2], b2fr[2][2];

    auto swzh = [](int row, int bc) { return row * 128 + (bc ^ ((row & 7) << 4)); };
    auto ldA = [&](int buf, int mb) {
#pragma unroll
        for (int m = 0; m < 4; ++m) {
            const int row = (mb + m) * 16 + lr;                 // 0..127 in half wr
#pragma unroll
            for (int ks = 0; ks < 2; ++ks)
                afr[m][ks] = *(const bf16x8*)&As[buf][wr][swzh(row, ks * 64 + lq * 16)];
        }
    };
    auto ldB = [&](int buf, int nb, bf16x8 (&bf)[2][2]) {
#pragma unroll
        for (int n = 0; n < 2; ++n) {
            const int r = wc * 64 + (nb + n) * 16 + lr;         // 0..255
#pragma unroll
            for (int ks = 0; ks < 2; ++ks)
                bf[n][ks] = *(const bf16x8*)&Bs[buf][r >> 7][swzh(r & 127, ks * 64 + lq * 16)];
        }
    };
    // ks OUTERMOST: dependent MFMAs spaced 8 apart; per-element accumulation
    // order unchanged (ks0 then ks1) -> bit-identical.
    auto quad = [&](int mb, int nb, bf16x8 (&bf)[2][2]) {
        __builtin_amdgcn_s_setprio(1);
#pragma unroll
        for (int ks = 0; ks < 2; ++ks)
#pragma unroll
            for (int m = 0; m < 4; ++m)
#pragma unroll
                for (int n = 0; n < 2; ++n)
                    acc[mb + m][nb + n] = __builtin_amdgcn_mfma_f32_16x16x32_bf16(
                        afr[m][ks], bf[n][ks], acc[mb + m][nb + n], 0, 0, 0);
        __builtin_amdgcn_s_setprio(0);
    };

    // ---- prologue: tile0 A->A0, B->B3[0]; tile1 B->B3[1]; 4 left in flight --
    stageA(0, 0, 0); stageA(0, 1, 0);
    stageB(0, 0, 0); stageB(0, 1, 0);
    stageB(1, 0, 1); stageB(1, 1, 1);
    WAIT_VM4();          // tile0's 8 loads landed; tile1's 4 B loads in flight
    BARRIER();

    // ---- main loop: ONE barrier + one counted vmcnt per K-tile ----
    // Entry invariant at tile t: A(t) in A-buf t&1, B(t) in B3[t%3], all landed
    // (guaranteed by end-of-t-1 vmcnt(4)); B(t+1)[4] in flight toward B3[(t+1)%3].
    // Hazard proofs (single barrier suffices):
    //   stageA(nxtA,t+1): A-buf nxtA last read in tile t-1; those ds_reads
    //     returned before their consuming MFMAs, all issued before the
    //     end-of-t-1 barrier < this DMA issue.
    //   stageB(preB,t+2): B3[preB] last held tile t-1's data, read in tile t-1
    //     behind the same barrier; NO reader of B3[preB] in tile t.
    //   end-of-t vmcnt(4): per-wave FIFO = B(t+1)[4, issued t-1] + A(t+1)[4,
    //     issued t top] + B(t+2)[4, issued t mid] = 12; wait(4) drains
    //     B(t+1) (2-tile lead) and A(t+1) (1-tile lead), leaves B(t+2).
    int curB = 0, preB = 2;          // curB = kt%3, preB = (kt+2)%3
#pragma unroll 1
    for (int kt = 0; kt < NT; ++kt) {
        const int curA = kt & 1, nxtA = curA ^ 1;

        // reads of tile t + prefetch A(t+1)
        ldA(curA, 0);
        ldB(curB, 0, b0fr);
        ldB(curB, 2, b2fr);
        if (kt + 1 < NT) { stageA(nxtA, 0, kt + 1); stageA(nxtA, 1, kt + 1); }

        quad(0, 0, b0fr);            // MFMA starts as soon as first frags land
        quad(0, 2, b2fr);

        ldA(curA, 4);                // reuse afr for mb4-7
        if (kt + 2 < NT) { stageB(preB, 0, kt + 2); stageB(preB, 1, kt + 2); }

        quad(4, 2, b2fr);
        quad(4, 0, b0fr);

        if (kt + 2 < NT)      { WAIT_VM4(); }   // t+1 landed; B(t+2) in flight
        else if (kt + 1 < NT) { WAIT_VM0(); }   // tail: drain last tile
        BARRIER();                   // single tile-boundary sync

        curB = (curB == 2) ? 0 : curB + 1;
        preB = (preB == 2) ? 0 : preB + 1;
    }

    // ---- epilogue: C/D layout col=lane&15, row=(lane>>4)*4+reg ----
    const float scl = scale_p[0];
#pragma unroll
    for (int m = 0; m < 8; ++m) {
        const int gm0 = tileM + wr * 128 + m * 16 + lq * 4;
#pragma unroll
        for (int n = 0; n < 4; ++n) {
            const int gn = tileN + wc * 64 + n * 16 + lr;
            float* cp = C + (size_t)gm0 * N_DIM + gn;
#pragma unroll
            for (int r = 0; r < 4; ++r)
                cp[(size_t)r * N_DIM] = acc[m][n][r] * scl;
        }
    }
}

// ===================== fallback (no workspace): reg-staged kernel ============
#define TILE_BYTES (BM * BK * 2)
__global__ __launch_bounds__(512, 2)
void qlin_gemm8(const void* __restrict__ Asrc, const void* __restrict__ Bsrc,
                const float* __restrict__ scale_p, float* __restrict__ C)
{
    __shared__ char As[2 * TILE_BYTES];
    __shared__ char Bs[2 * TILE_BYTES];

    const int tid = threadIdx.x;
    const int nwg = (M_DIM / BM) * (N_DIM / BN);
    const int cpx = nwg / 8;
    const int bid = ((int)blockIdx.x % 8) * cpx + (int)blockIdx.x / 8;
    const int tileM = (bid / (N_DIM / BN)) * BM;
    const int tileN = (bid % (N_DIM / BN)) * BN;

    const int lane = tid & 63;
    const int wid  = tid >> 6;
    const int wr   = wid >> 2;
    const int wc   = wid & 3;
    const int lr   = lane & 15;
    const int lq   = lane >> 4;

    f32x4  aF[8]; i32x4 wF[8];

    const float* ag0 = (const float*)Asrc + (size_t)(tileM + (tid >> 4)) * K_DIM + (tid & 15) * 4;
    const int*   bg0 = (const int*)Bsrc  + (size_t)(tileN + (tid >> 4)) * K_DIM + (tid & 15) * 4;

    auto stage_load = [&](int kt) {
#pragma unroll
        for (int i = 0; i < 8; ++i)
            aF[i] = *(const f32x4*)(ag0 + (size_t)(32 * i) * K_DIM + kt * BK);
#pragma unroll
        for (int i = 0; i < 8; ++i)
            wF[i] = *(const i32x4*)(bg0 + (size_t)(32 * i) * K_DIM + kt * BK);
    };
    auto stage_writeA = [&](int nxt) {
        char* dst = As + nxt * TILE_BYTES;
#pragma unroll
        for (int i = 0; i < 8; ++i) {
            u32x2 p;
            p[0] = pack_bf16_trunc(aF[i][0], aF[i][1]);
            p[1] = pack_bf16_trunc(aF[i][2], aF[i][3]);
            *(u32x2*)(dst + swzb((tid >> 4) + 32 * i, (tid & 15) * 8)) = p;
        }
    };
    auto stage_writeB = [&](int nxt) {
        char* dst = Bs + nxt * TILE_BYTES;
#pragma unroll
        for (int i = 0; i < 8; ++i) {
            u32x2 p;
            p[0] = pack_bf16_trunc((float)wF[i][0], (float)wF[i][1]);
            p[1] = pack_bf16_trunc((float)wF[i][2], (float)wF[i][3]);
            *(u32x2*)(dst + swzb((tid >> 4) + 32 * i, (tid & 15) * 8)) = p;
        }
    };

    f32x4  acc[8][4] = {};
    bf16x8 afr[4][2], bfr[2][2];

    auto ldA = [&](const char* buf, int mb) {
#pragma unroll
        for (int m = 0; m < 4; ++m) {
            const int row = wr * 128 + (mb + m) * 16 + lr;
#pragma unroll
            for (int ks = 0; ks < 2; ++ks)
                afr[m][ks] = *(const bf16x8*)(buf + swzb(row, ks * 64 + lq * 16));
        }
    };
    auto ldB = [&](const char* buf, int nb) {
#pragma unroll
        for (int n = 0; n < 2; ++n) {
            const int row = wc * 64 + (nb + n) * 16 + lr;
#pragma unroll
            for (int ks = 0; ks < 2; ++ks)
                bfr[n][ks] = *(const bf16x8*)(buf + swzb(row, ks * 64 + lq * 16));
        }
    };
    auto quad = [&](int mb, int nb) {
        __builtin_amdgcn_s_setprio(1);
#pragma unroll
        for (int ks = 0; ks < 2; ++ks)
#pragma unroll
            for (int m = 0; m < 4; ++m)
#pragma unroll
                for (int n = 0; n < 2; ++n)
                    acc[mb + m][nb + n] = __builtin_amdgcn_mfma_f32_16x16x32_bf16(
                        afr[m][ks], bfr[n][ks], acc[mb + m][nb + n], 0, 0, 0);
        __builtin_amdgcn_s_setprio(0);
    };

    stage_load(0);
    stage_writeA(0);
    stage_writeB(0);
    __syncthreads();

#pragma unroll 1
    for (int kt = 0; kt < NT; ++kt) {
        const int cur = kt & 1, nxt = cur ^ 1;
        const bool more = (kt + 1) < NT;
        const char* Ab = As + cur * TILE_BYTES;
        const char* Bb = Bs + cur * TILE_BYTES;

        if (more) stage_load(kt + 1);

        ldA(Ab, 0); ldB(Bb, 0); quad(0, 0);
        ldB(Bb, 2);             quad(0, 2);
        ldA(Ab, 4);
        if (more) stage_writeA(nxt);
        quad(4, 2);
        ldB(Bb, 0);
        if (more) stage_writeB(nxt);
        quad(4, 0);

        __syncthreads();
    }

    const float scl = scale_p[0];
#pragma unroll
    for (int m = 0; m < 8; ++m) {
        const int gm0 = tileM + wr * 128 + m * 16 + lq * 4;
#pragma unroll
        for (int n = 0; n < 4; ++n) {
            const int gn = tileN + wc * 64 + n * 16 + lr;
            float* cp = C + (size_t)gm0 * N_DIM + gn;
#pragma unroll
            for (int r = 0; r < 4; ++r)
                cp[(size_t)r * N_DIM] = acc[m][n][r] * scl;
        }
    }
}

extern "C" void kernel_launch(void* const* d_in, const int* in_sizes, int n_in,
                              void* d_out, int out_size, void* d_ws, size_t ws_size,
                              hipStream_t stream)
{
    (void)in_sizes; (void)n_in; (void)out_size;
    const float* X     = (const float*)d_in[0];
    const int*   Wq    = (const int*)d_in[1];      // int8-valued, delivered as int32
    const float* scale = (const float*)d_in[2];
    float* C = (float*)d_out;

    const size_t xbytes = (size_t)M_DIM * K_DIM * sizeof(short);   // 64 MiB
    const size_t wbytes = (size_t)N_DIM * K_DIM * sizeof(short);   // 32 MiB

    if (ws_size >= xbytes + wbytes) {
        short* Xb = (short*)d_ws;
        short* Wb = (short*)((char*)d_ws + xbytes);
        qlin_convert_xw<<<dim3(NXB + NWB), dim3(256), 0, stream>>>(X, Wq, Xb, Wb);
        qlin_gemm_p<<<dim3((M_DIM / BM) * (N_DIM / BN)), dim3(512), 0, stream>>>(Xb, Wb, scale, C);
    } else {
        qlin_gemm8<<<dim3((M_DIM / BM) * (N_DIM / BN)), dim3(512), 0, stream>>>(X, Wq, scale, C);
    }
}